// Round 5
// baseline (222.565 us; speedup 1.0000x reference)
//
#include <hip/hip_runtime.h>

#define BLOCK 1024
#define NW (BLOCK / 64)
#define FPSCALE 8192.0f        // 2^13 fixed-point scale for histogram mass
#define INVSCALE 0x1p-13f

// inclusive scan across a 64-lane wave (lane order = index order)
__device__ __forceinline__ float wincl(float v, int lane) {
#pragma unroll
    for (int o = 1; o < 64; o <<= 1) {
        float x = __shfl_up(v, o, 64);
        if (lane >= o) v += x;
    }
    return v;
}

// Walk buckets in DESCENDING value order; find first bucket where running
// inclusive mass exceeds limit. One full wave executes.
__device__ __forceinline__ void find_crit_desc(const float* h, int n, int seg,
                                               float limit, int lane, int* out_b) {
    float segsum = 0.f;
    int start = n - 1 - lane * seg;
    for (int k = 0; k < seg; k++) segsum += h[start - k];
    float incl = wincl(segsum, lane);
    unsigned long long mk = __ballot(incl > limit);
    if (mk == 0ULL) { *out_b = 0; return; }
    int fl = __ffsll(mk) - 1;
    float base = __shfl(incl, fl, 64) - __shfl(segsum, fl, 64);
    int sstart = n - 1 - fl * seg;
    float v = (lane < seg) ? h[sstart - lane] : 0.f;
    float incl2 = wincl(v, lane);
    unsigned long long mk2 = __ballot((lane < seg) && (base + incl2 > limit));
    int k2 = mk2 ? (__ffsll(mk2) - 1) : (seg - 1);
    *out_b = sstart - k2;
}

// monotone (total-order) key of a float's bit pattern: 3 ops
#define OKEY(bb) ((bb) ^ ((unsigned)((int)(bb) >> 31) | 0x80000000u))

#define LD4(j) (*(const float4*)(row + (j)))

#define P1(xx) { unsigned kk = OKEY(__float_as_uint(xx)); \
                 float e = __expf((xx) * inv_t); \
                 atomicAdd(&histbuf[((kk >> 21) << 2) | rep], \
                           (unsigned)(e * FPSCALE + 0.5f)); }

#define P2(xx, ss) { unsigned kk = OKEY(__float_as_uint(xx)); \
                     float e = __expf((xx) * inv_t); \
                     if (kk >= Tlow) ss += e; }

// ============================ multi-kernel path =============================
// K1: half-row L1 histogram -> private partial histogram in workspace.
// 2 blocks/CU (VGPR<=64 via launch_bounds) => 32 waves/CU latency hiding.
__global__ __launch_bounds__(BLOCK, 8) void ns_hist(
    const float* __restrict__ logits, const int* __restrict__ temp,
    unsigned* __restrict__ part, int Vv) {
    const int bid = blockIdx.x;
    const int b = bid >> 1, h = bid & 1;
    const float* __restrict__ row = logits + (size_t)b * (size_t)Vv;
    const int t = threadIdx.x;
    const int rep = t & 3;

    __shared__ __align__(16) unsigned histbuf[8192];  // 4 replicas x 2048

    const float inv_t = 1.0f / (float)temp[0];
    const int S = BLOCK * 4;
    const int HL = (((Vv + 1) >> 1) + 3) & ~3;        // 16B-aligned half length
    const int lo = h * HL;
    const int hi = min(Vv, lo + HL);
    const int hi4 = (hi > lo) ? lo + ((hi - lo) & ~3) : lo;

    for (int i = t; i < 8192; i += BLOCK) histbuf[i] = 0u;
    __syncthreads();

    {
        int i = lo + t * 4;
        for (; i + 3 * S + 3 < hi4; i += 4 * S) {
            float4 a = LD4(i), b4 = LD4(i + S), c = LD4(i + 2 * S), d = LD4(i + 3 * S);
            P1(a.x); P1(a.y); P1(a.z); P1(a.w);
            P1(b4.x); P1(b4.y); P1(b4.z); P1(b4.w);
            P1(c.x); P1(c.y); P1(c.z); P1(c.w);
            P1(d.x); P1(d.y); P1(d.z); P1(d.w);
        }
        for (; i + 3 < hi4; i += S) { float4 a = LD4(i); P1(a.x); P1(a.y); P1(a.z); P1(a.w); }
        for (int j = hi4 + t; j < hi; j += BLOCK) P1(row[j]);
    }
    __syncthreads();

    // merge 4 replicas -> partial histogram (plain stores; order-independent u32)
    unsigned* __restrict__ dst = part + (size_t)bid * 2048;
    for (int i = t; i < 2048; i += BLOCK) {
        uint4 m4 = *(const uint4*)&histbuf[i << 2];
        dst[i] = m4.x + m4.y + m4.z + m4.w;
    }
}

// K2: merge partials, total Z, descending bucket walk -> Tlow per row.
__global__ __launch_bounds__(BLOCK) void ns_walk(
    const unsigned* __restrict__ part, unsigned* __restrict__ tlow, int Bn) {
    const int b = blockIdx.x;
    const int t = threadIdx.x;
    const int lane = t & 63;
    const int wave = t >> 6;

    __shared__ float mg[2048];
    __shared__ float sweep[NW];

    const unsigned* __restrict__ pa = part + (size_t)(b * 2) * 2048;
    const unsigned* __restrict__ pb = part + (size_t)(b * 2 + 1) * 2048;

    float zp = 0.f;
    for (int i = t; i < 2048; i += BLOCK) {
        float m = (float)(pa[i] + pb[i]) * INVSCALE;
        mg[i] = m;
        zp += m;
    }
#pragma unroll
    for (int o = 32; o >= 1; o >>= 1) zp += __shfl_xor(zp, o, 64);
    if (lane == 0) sweep[wave] = zp;
    __syncthreads();
    float Z = 0.f;
    for (int w = 0; w < NW; w++) Z += sweep[w];
    const float limit = 0.9f * Z;

    if (wave == 0) {
        int b1w;
        find_crit_desc(mg, 2048, 32, limit, lane, &b1w);
        if (lane == 0) tlow[b] = (unsigned)b1w << 21;
    }
}

// K3: kept-mass chunk sums for half the chunks (identical lane mapping/reduce
// tree as the verified single-kernel pass 2 -> bitwise-identical csum).
__global__ __launch_bounds__(BLOCK, 8) void ns_csum(
    const float* __restrict__ logits, const int* __restrict__ temp,
    const unsigned* __restrict__ tlow, float* __restrict__ csum, int Vv) {
    const int bid = blockIdx.x;
    const int b = bid >> 1, h = bid & 1;
    const float* __restrict__ row = logits + (size_t)b * (size_t)Vv;
    const int t = threadIdx.x;
    const int lane = t & 63;
    const int wave = t >> 6;

    const float inv_t = 1.0f / (float)temp[0];
    const unsigned Tlow = tlow[b];
    const int nch = (Vv + 1023) >> 10;
    const int nchh = (nch + 1) >> 1;
    const int clo = h * nchh;
    const int chi = min(nch, clo + nchh);
    float* __restrict__ cs = csum + (size_t)b * 128;

    for (int c0 = clo + wave; c0 < chi; c0 += 2 * NW) {
        const int c1 = c0 + NW;
        const bool haveB = (c1 < chi);
        float s0 = 0.f, s1 = 0.f;
        const int bA = c0 << 10, bB = c1 << 10;
        if (bA + 1024 <= Vv && (!haveB || bB + 1024 <= Vv)) {
            float4 a0 = LD4(bA + lane * 4);
            float4 a1 = LD4(bA + 256 + lane * 4);
            float4 a2 = LD4(bA + 512 + lane * 4);
            float4 a3 = LD4(bA + 768 + lane * 4);
            if (haveB) {
                float4 b0 = LD4(bB + lane * 4);
                float4 b1v = LD4(bB + 256 + lane * 4);
                float4 b2 = LD4(bB + 512 + lane * 4);
                float4 b3 = LD4(bB + 768 + lane * 4);
                P2(b0.x, s1); P2(b0.y, s1); P2(b0.z, s1); P2(b0.w, s1);
                P2(b1v.x, s1); P2(b1v.y, s1); P2(b1v.z, s1); P2(b1v.w, s1);
                P2(b2.x, s1); P2(b2.y, s1); P2(b2.z, s1); P2(b2.w, s1);
                P2(b3.x, s1); P2(b3.y, s1); P2(b3.z, s1); P2(b3.w, s1);
            }
            P2(a0.x, s0); P2(a0.y, s0); P2(a0.z, s0); P2(a0.w, s0);
            P2(a1.x, s0); P2(a1.y, s0); P2(a1.z, s0); P2(a1.w, s0);
            P2(a2.x, s0); P2(a2.y, s0); P2(a2.z, s0); P2(a2.w, s0);
            P2(a3.x, s0); P2(a3.y, s0); P2(a3.z, s0); P2(a3.w, s0);
        } else {
            for (int q = 0; q < 16; q++) {
                int i = bA + (q << 6) + lane;
                if (i < Vv) { float x = row[i]; P2(x, s0); }
            }
            if (haveB) {
                for (int q = 0; q < 16; q++) {
                    int i = bB + (q << 6) + lane;
                    if (i < Vv) { float x = row[i]; P2(x, s1); }
                }
            }
        }
#pragma unroll
        for (int o = 32; o >= 1; o >>= 1) s0 += __shfl_xor(s0, o, 64);
        if (lane == 0) cs[c0] = s0;
        if (haveB) {
#pragma unroll
            for (int o = 32; o >= 1; o >>= 1) s1 += __shfl_xor(s1, o, 64);
            if (lane == 0) cs[c1] = s1;
        }
    }
}

// K4: per-row inverse-CDF walk over chunk sums -> token. One wave per row.
__global__ __launch_bounds__(64) void ns_pick(
    const float* __restrict__ logits, const float* __restrict__ uvec,
    const int* __restrict__ temp, const unsigned* __restrict__ tlow,
    const float* __restrict__ csum, int* __restrict__ out, int Vv) {
    const int b = blockIdx.x;
    const float* __restrict__ row = logits + (size_t)b * (size_t)Vv;
    const int lane = threadIdx.x;
    const float inv_t = 1.0f / (float)temp[0];
    const unsigned Tlow = tlow[b];
    const int nch = (Vv + 1023) >> 10;
    const float* __restrict__ cs = csum + (size_t)b * 128;

    float c0v = (2 * lane < nch) ? cs[2 * lane] : 0.f;
    float c1v = (2 * lane + 1 < nch) ? cs[2 * lane + 1] : 0.f;
    float segsum = c0v + c1v;
    float incl = wincl(segsum, lane);
    float total = __shfl(incl, 63, 64);                // Z_kept
    const float U = uvec[b] * total;
    unsigned long long mk = __ballot(incl >= U);
    int token;
    if (mk == 0ULL) {
        token = Vv;
    } else {
        int fl = __ffsll(mk) - 1;
        float base = __shfl(incl, fl, 64) - __shfl(segsum, fl, 64);
        float v = (lane < 2 && fl * 2 + lane < nch) ? cs[fl * 2 + lane] : 0.f;
        float incl2 = wincl(v, lane);
        unsigned long long mk2 = __ballot((lane < 2) && (base + incl2 >= U));
        int k2i = mk2 ? (__ffsll(mk2) - 1) : 1;
        int cx = fl * 2 + k2i;                         // crossing chunk
        float B = base + __shfl(incl2, k2i, 64) - __shfl(v, k2i, 64);
        int cb = cx << 10;
        float vv[16];
#pragma unroll
        for (int r = 0; r < 16; r++) {
            int idx = cb + r * 64 + lane;
            vv[r] = (idx < Vv) ? row[idx] : -1e30f;
        }
        int cnt2 = 0;
#pragma unroll
        for (int r = 0; r < 16; r++) {
            int idx = cb + r * 64 + lane;
            unsigned kk = OKEY(__float_as_uint(vv[r]));
            float e = __expf(vv[r] * inv_t);
            float keep = (kk >= Tlow) ? e : 0.f;
            float is = wincl(keep, lane);
            unsigned long long mm = __ballot((idx < Vv) && (B + is < U));
            cnt2 += __popcll(mm);
            B += __shfl(is, 63, 64);
        }
        token = cb + cnt2;
    }
    if (lane == 0) out[b] = (token < Vv - 1) ? token : (Vv - 1);
}

// ===================== fallback: verified single-kernel path ================
__global__ __launch_bounds__(BLOCK) void NucleusSampling_79336635892529_kernel(
    const float* __restrict__ logits, const float* __restrict__ uvec,
    const int* __restrict__ temp, int* __restrict__ out, int Vv) {
    const int b = blockIdx.x;
    const float* __restrict__ row = logits + (size_t)b * (size_t)Vv;
    const int t = threadIdx.x;
    const int lane = t & 63;
    const int wave = t >> 6;
    const int rep = lane & 3;

    __shared__ __align__(16) unsigned histbuf[8192];
    __shared__ float mg[2048];
    __shared__ float sweep[NW];
    __shared__ float csum[128];
    __shared__ int shb1;

    const float inv_t = 1.0f / (float)temp[0];
    const int V4 = Vv & ~3;
    const int S = BLOCK * 4;
    const int nch = (Vv + 1023) >> 10;

    for (int i = t; i < 8192; i += BLOCK) histbuf[i] = 0u;
    __syncthreads();
    {
        int i = t * 4;
        for (; i + 3 * S + 3 < V4; i += 4 * S) {
            float4 a = LD4(i), b4 = LD4(i + S), c = LD4(i + 2 * S), d = LD4(i + 3 * S);
            P1(a.x); P1(a.y); P1(a.z); P1(a.w);
            P1(b4.x); P1(b4.y); P1(b4.z); P1(b4.w);
            P1(c.x); P1(c.y); P1(c.z); P1(c.w);
            P1(d.x); P1(d.y); P1(d.z); P1(d.w);
        }
        for (; i < V4; i += S) { float4 a = LD4(i); P1(a.x); P1(a.y); P1(a.z); P1(a.w); }
        for (int j = V4 + t; j < Vv; j += BLOCK) P1(row[j]);
    }
    __syncthreads();
    float zp = 0.f;
    for (int i = t; i < 2048; i += BLOCK) {
        uint4 m4 = *(const uint4*)&histbuf[i << 2];
        float m = (float)(m4.x + m4.y + m4.z + m4.w) * INVSCALE;
        mg[i] = m;
        zp += m;
    }
#pragma unroll
    for (int o = 32; o >= 1; o >>= 1) zp += __shfl_xor(zp, o, 64);
    if (lane == 0) sweep[wave] = zp;
    __syncthreads();
    float Z = 0.f;
    for (int w = 0; w < NW; w++) Z += sweep[w];
    const float limit = 0.9f * Z;
    if (wave == 0) {
        int b1w;
        find_crit_desc(mg, 2048, 32, limit, lane, &b1w);
        if (lane == 0) shb1 = b1w;
    }
    if (t < 128 && t >= nch) csum[t] = 0.f;
    __syncthreads();
    const unsigned Tlow = (unsigned)shb1 << 21;

    for (int c0 = wave; c0 < nch; c0 += 2 * NW) {
        const int c1 = c0 + NW;
        const bool haveB = (c1 < nch);
        float s0 = 0.f, s1 = 0.f;
        const int bA = c0 << 10, bB = c1 << 10;
        if (bA + 1024 <= Vv && (!haveB || bB + 1024 <= Vv)) {
            float4 a0 = LD4(bA + lane * 4);
            float4 a1 = LD4(bA + 256 + lane * 4);
            float4 a2 = LD4(bA + 512 + lane * 4);
            float4 a3 = LD4(bA + 768 + lane * 4);
            if (haveB) {
                float4 b0 = LD4(bB + lane * 4);
                float4 b1v = LD4(bB + 256 + lane * 4);
                float4 b2 = LD4(bB + 512 + lane * 4);
                float4 b3 = LD4(bB + 768 + lane * 4);
                P2(b0.x, s1); P2(b0.y, s1); P2(b0.z, s1); P2(b0.w, s1);
                P2(b1v.x, s1); P2(b1v.y, s1); P2(b1v.z, s1); P2(b1v.w, s1);
                P2(b2.x, s1); P2(b2.y, s1); P2(b2.z, s1); P2(b2.w, s1);
                P2(b3.x, s1); P2(b3.y, s1); P2(b3.z, s1); P2(b3.w, s1);
            }
            P2(a0.x, s0); P2(a0.y, s0); P2(a0.z, s0); P2(a0.w, s0);
            P2(a1.x, s0); P2(a1.y, s0); P2(a1.z, s0); P2(a1.w, s0);
            P2(a2.x, s0); P2(a2.y, s0); P2(a2.z, s0); P2(a2.w, s0);
            P2(a3.x, s0); P2(a3.y, s0); P2(a3.z, s0); P2(a3.w, s0);
        } else {
            for (int q = 0; q < 16; q++) {
                int i = bA + (q << 6) + lane;
                if (i < Vv) { float x = row[i]; P2(x, s0); }
            }
            if (haveB) {
                for (int q = 0; q < 16; q++) {
                    int i = bB + (q << 6) + lane;
                    if (i < Vv) { float x = row[i]; P2(x, s1); }
                }
            }
        }
#pragma unroll
        for (int o = 32; o >= 1; o >>= 1) s0 += __shfl_xor(s0, o, 64);
        if (lane == 0) csum[c0] = s0;
        if (haveB) {
#pragma unroll
            for (int o = 32; o >= 1; o >>= 1) s1 += __shfl_xor(s1, o, 64);
            if (lane == 0) csum[c1] = s1;
        }
    }
    __syncthreads();

    if (wave == 0) {
        float segsum = csum[lane * 2] + csum[lane * 2 + 1];
        float incl = wincl(segsum, lane);
        float total = __shfl(incl, 63, 64);
        const float U = uvec[b] * total;
        unsigned long long mk = __ballot(incl >= U);
        int token;
        if (mk == 0ULL) {
            token = Vv;
        } else {
            int fl = __ffsll(mk) - 1;
            float base = __shfl(incl, fl, 64) - __shfl(segsum, fl, 64);
            float v = (lane < 2) ? csum[fl * 2 + lane] : 0.f;
            float incl2 = wincl(v, lane);
            unsigned long long mk2 = __ballot((lane < 2) && (base + incl2 >= U));
            int k2i = mk2 ? (__ffsll(mk2) - 1) : 1;
            int cx = fl * 2 + k2i;
            float B = base + __shfl(incl2, k2i, 64) - __shfl(v, k2i, 64);
            int cb = cx << 10;
            float vv[16];
#pragma unroll
            for (int r = 0; r < 16; r++) {
                int idx = cb + r * 64 + lane;
                vv[r] = (idx < Vv) ? row[idx] : -1e30f;
            }
            int cnt2 = 0;
#pragma unroll
            for (int r = 0; r < 16; r++) {
                int idx = cb + r * 64 + lane;
                unsigned kk = OKEY(__float_as_uint(vv[r]));
                float e = __expf(vv[r] * inv_t);
                float keep = (kk >= Tlow) ? e : 0.f;
                float is = wincl(keep, lane);
                unsigned long long mm = __ballot((idx < Vv) && (B + is < U));
                cnt2 += __popcll(mm);
                B += __shfl(is, 63, 64);
            }
            token = cb + cnt2;
        }
        if (lane == 0) out[b] = (token < Vv - 1) ? token : (Vv - 1);
    }
}

extern "C" void kernel_launch(void* const* d_in, const int* in_sizes, int n_in,
                              void* d_out, int out_size, void* d_ws, size_t ws_size,
                              hipStream_t stream) {
    const float* logits = (const float*)d_in[0];
    const float* u = (const float*)d_in[1];
    const int* temp = (const int*)d_in[2];
    int* out = (int*)d_out;
    int B = in_sizes[1];
    int V = in_sizes[0] / B;

    size_t sz_hist = (size_t)B * 2 * 2048 * sizeof(unsigned);
    size_t off_tlow = sz_hist;
    size_t sz_tlow = ((size_t)B * sizeof(unsigned) + 255) & ~(size_t)255;
    size_t off_csum = off_tlow + sz_tlow;
    size_t need = off_csum + (size_t)B * 128 * sizeof(float);

    if (d_ws != nullptr && ws_size >= need) {
        unsigned* part = (unsigned*)d_ws;
        unsigned* tlow = (unsigned*)((char*)d_ws + off_tlow);
        float* csum = (float*)((char*)d_ws + off_csum);
        ns_hist<<<2 * B, BLOCK, 0, stream>>>(logits, temp, part, V);
        ns_walk<<<B, BLOCK, 0, stream>>>(part, tlow, B);
        ns_csum<<<2 * B, BLOCK, 0, stream>>>(logits, temp, tlow, csum, V);
        ns_pick<<<B, 64, 0, stream>>>(logits, u, temp, tlow, csum, out, V);
    } else {
        NucleusSampling_79336635892529_kernel<<<B, BLOCK, 0, stream>>>(
            logits, u, temp, out, V);
    }
}

// Round 7
// 205.473 us; speedup vs baseline: 1.0832x; 1.0832x over previous
//
#include <hip/hip_runtime.h>

#define BLOCK 1024
#define NW (BLOCK / 64)
#define FPSCALE 8192.0f        // 2^13 fixed-point scale for histogram mass
#define INVSCALE 0x1p-13f

// inclusive scan across a 64-lane wave (lane order = index order)
__device__ __forceinline__ float wincl(float v, int lane) {
#pragma unroll
    for (int o = 1; o < 64; o <<= 1) {
        float x = __shfl_up(v, o, 64);
        if (lane >= o) v += x;
    }
    return v;
}

// Walk buckets in DESCENDING value order; find first bucket where running
// inclusive mass exceeds limit. One full wave executes.
__device__ __forceinline__ void find_crit_desc(const float* h, int n, int seg,
                                               float limit, int lane, int* out_b) {
    float segsum = 0.f;
    int start = n - 1 - lane * seg;
    for (int k = 0; k < seg; k++) segsum += h[start - k];
    float incl = wincl(segsum, lane);
    unsigned long long mk = __ballot(incl > limit);
    if (mk == 0ULL) { *out_b = 0; return; }
    int fl = __ffsll(mk) - 1;
    float base = __shfl(incl, fl, 64) - __shfl(segsum, fl, 64);
    int sstart = n - 1 - fl * seg;
    float v = (lane < seg) ? h[sstart - lane] : 0.f;
    float incl2 = wincl(v, lane);
    unsigned long long mk2 = __ballot((lane < seg) && (base + incl2 > limit));
    int k2 = mk2 ? (__ffsll(mk2) - 1) : (seg - 1);
    *out_b = sstart - k2;
}

// monotone (total-order) key of a float's bit pattern: 3 ops
#define OKEY(bb) ((bb) ^ ((unsigned)((int)(bb) >> 31) | 0x80000000u))

#define LD4(j) (*(const float4*)(row + (j)))

#define P1(xx) { unsigned kk = OKEY(__float_as_uint(xx)); \
                 float e = __expf((xx) * inv_t); \
                 atomicAdd(&histbuf[((kk >> 21) << 2) | rep], \
                           (unsigned)(e * FPSCALE + 0.5f)); }

#define P2(xx, ss) { unsigned kk = OKEY(__float_as_uint(xx)); \
                     float e = __expf((xx) * inv_t); \
                     if (kk >= Tlow) ss += e; }

// Single kernel. Chunk-local pass 1 with register retention of half the row:
// wave w owns chunks 8w..8w+7 (1024 elems each). Chunks 8w..8w+3 are kept in
// r[4][4] (64 VGPR/lane) across the histogram walk, so pass 2 only re-reads
// the other half (L3-resident). Element->lane mapping and per-lane summation
// order are identical to the verified 75.7us kernel => bitwise-same output.
__global__ __launch_bounds__(BLOCK) void NucleusSampling_79336635892529_kernel(
    const float* __restrict__ logits, const float* __restrict__ uvec,
    const int* __restrict__ temp, int* __restrict__ out, int Vv) {
    const int b = blockIdx.x;
    const float* __restrict__ row = logits + (size_t)b * (size_t)Vv;
    const int t = threadIdx.x;
    const int lane = t & 63;
    const int wave = t >> 6;
    const int rep = lane & 3;              // histogram replica index

    __shared__ __align__(16) unsigned histbuf[8192]; // 4 replicas x 2048 buckets
    __shared__ float mg[2048];                       // merged histogram
    __shared__ float sweep[NW];
    __shared__ float csum[128];                      // 1024-elem chunk sums
    __shared__ int shb1;

    const float inv_t = 1.0f / (float)temp[0];
    const int nch = (Vv + 1023) >> 10;               // requires V <= 131072

    for (int i = t; i < 8192; i += BLOCK) histbuf[i] = 0u;
    if (t < 128) csum[t] = 0.f;                      // empty chunks stay 0
    __syncthreads();

    // ---------------- Pass 1: chunk-local histogram + register retention ------
    const int base0 = wave << 13;                    // wave's first element (8 chunks)
    float4 r[4][4];                                  // retained: chunks c0..c0+3

    // load retained chunks (16 float4 in flight, 16KB contiguous per wave)
#pragma unroll
    for (int c = 0; c < 4; c++) {
        const int bA = base0 + (c << 10);
        if (bA + 1024 <= Vv) {
#pragma unroll
            for (int q = 0; q < 4; q++) r[c][q] = LD4(bA + (q << 8) + (lane << 2));
        }
    }
    // histogram retained chunks
#pragma unroll
    for (int c = 0; c < 4; c++) {
        const int bA = base0 + (c << 10);
        if (bA + 1024 <= Vv) {
#pragma unroll
            for (int q = 0; q < 4; q++) {
                P1(r[c][q].x); P1(r[c][q].y); P1(r[c][q].z); P1(r[c][q].w);
            }
        } else if (bA < Vv) {
            for (int qq = 0; qq < 16; qq++) {
                int i = bA + (qq << 6) + lane;
                if (i < Vv) P1(row[i]);
            }
        }
    }
    // transient chunks c0+4..c0+7, processed as 2 pairs (regs reused)
#pragma unroll
    for (int p = 0; p < 2; p++) {
        const int bA = base0 + ((4 + 2 * p) << 10);
        const int bB = bA + 1024;
        const bool fa = (bA + 1024 <= Vv), fb = (bB + 1024 <= Vv);
        float4 ta[4], tb[4];
        if (fa) {
#pragma unroll
            for (int q = 0; q < 4; q++) ta[q] = LD4(bA + (q << 8) + (lane << 2));
        }
        if (fb) {
#pragma unroll
            for (int q = 0; q < 4; q++) tb[q] = LD4(bB + (q << 8) + (lane << 2));
        }
        if (fa) {
#pragma unroll
            for (int q = 0; q < 4; q++) { P1(ta[q].x); P1(ta[q].y); P1(ta[q].z); P1(ta[q].w); }
        } else if (bA < Vv) {
            for (int qq = 0; qq < 16; qq++) {
                int i = bA + (qq << 6) + lane;
                if (i < Vv) P1(row[i]);
            }
        }
        if (fb) {
#pragma unroll
            for (int q = 0; q < 4; q++) { P1(tb[q].x); P1(tb[q].y); P1(tb[q].z); P1(tb[q].w); }
        } else if (bB < Vv) {
            for (int qq = 0; qq < 16; qq++) {
                int i = bB + (qq << 6) + lane;
                if (i < Vv) P1(row[i]);
            }
        }
    }
    __syncthreads();

    // merge replicas (one b128 read) + total mass Z
    float zp = 0.f;
    for (int i = t; i < 2048; i += BLOCK) {
        uint4 m4 = *(const uint4*)&histbuf[i << 2];
        float m = (float)(m4.x + m4.y + m4.z + m4.w) * INVSCALE;
        mg[i] = m;
        zp += m;
    }
#pragma unroll
    for (int o = 32; o >= 1; o >>= 1) zp += __shfl_xor(zp, o, 64);
    if (lane == 0) sweep[wave] = zp;
    __syncthreads();
    float Z = 0.f;
    for (int w = 0; w < NW; w++) Z += sweep[w];
    const float limit = 0.9f * Z;

    // L1 walk -> critical bucket b1. Keep-set = { okey >= b1<<21 }.
    if (wave == 0) {
        int b1w;
        find_crit_desc(mg, 2048, 32, limit, lane, &b1w);
        if (lane == 0) shb1 = b1w;
    }
    __syncthreads();
    const unsigned Tlow = (unsigned)shb1 << 21;

    // ---------------- Pass 2: kept-mass chunk sums --------------------------
    // retained chunks: pure VALU from registers (no memory reads)
#pragma unroll
    for (int c = 0; c < 4; c++) {
        const int cc = (wave << 3) + c;
        const int bA = base0 + (c << 10);
        if (bA + 1024 <= Vv) {
            float s = 0.f;
#pragma unroll
            for (int q = 0; q < 4; q++) {
                P2(r[c][q].x, s); P2(r[c][q].y, s); P2(r[c][q].z, s); P2(r[c][q].w, s);
            }
#pragma unroll
            for (int o = 32; o >= 1; o >>= 1) s += __shfl_xor(s, o, 64);
            if (lane == 0) csum[cc] = s;
        } else if (bA < Vv) {
            float s = 0.f;
            for (int qq = 0; qq < 16; qq++) {
                int i = bA + (qq << 6) + lane;
                if (i < Vv) { float x = row[i]; P2(x, s); }
            }
#pragma unroll
            for (int o = 32; o >= 1; o >>= 1) s += __shfl_xor(s, o, 64);
            if (lane == 0) csum[cc] = s;
        }
    }
    // transient chunks: re-read (L3-resident), 2 chunks of loads in flight
#pragma unroll
    for (int p = 0; p < 2; p++) {
        const int ccA = (wave << 3) + 4 + 2 * p;
        const int ccB = ccA + 1;
        const int bA = base0 + ((4 + 2 * p) << 10);
        const int bB = bA + 1024;
        const bool fa = (bA + 1024 <= Vv), fb = (bB + 1024 <= Vv);
        float4 ta[4], tb[4];
        if (fa) {
#pragma unroll
            for (int q = 0; q < 4; q++) ta[q] = LD4(bA + (q << 8) + (lane << 2));
        }
        if (fb) {
#pragma unroll
            for (int q = 0; q < 4; q++) tb[q] = LD4(bB + (q << 8) + (lane << 2));
        }
        if (fa) {
            float s = 0.f;
#pragma unroll
            for (int q = 0; q < 4; q++) {
                P2(ta[q].x, s); P2(ta[q].y, s); P2(ta[q].z, s); P2(ta[q].w, s);
            }
#pragma unroll
            for (int o = 32; o >= 1; o >>= 1) s += __shfl_xor(s, o, 64);
            if (lane == 0) csum[ccA] = s;
        } else if (bA < Vv) {
            float s = 0.f;
            for (int qq = 0; qq < 16; qq++) {
                int i = bA + (qq << 6) + lane;
                if (i < Vv) { float x = row[i]; P2(x, s); }
            }
#pragma unroll
            for (int o = 32; o >= 1; o >>= 1) s += __shfl_xor(s, o, 64);
            if (lane == 0) csum[ccA] = s;
        }
        if (fb) {
            float s = 0.f;
#pragma unroll
            for (int q = 0; q < 4; q++) {
                P2(tb[q].x, s); P2(tb[q].y, s); P2(tb[q].z, s); P2(tb[q].w, s);
            }
#pragma unroll
            for (int o = 32; o >= 1; o >>= 1) s += __shfl_xor(s, o, 64);
            if (lane == 0) csum[ccB] = s;
        } else if (bB < Vv) {
            float s = 0.f;
            for (int qq = 0; qq < 16; qq++) {
                int i = bB + (qq << 6) + lane;
                if (i < Vv) { float x = row[i]; P2(x, s); }
            }
#pragma unroll
            for (int o = 32; o >= 1; o >>= 1) s += __shfl_xor(s, o, 64);
            if (lane == 0) csum[ccB] = s;
        }
    }
    __syncthreads();

    // ---------------- final: locate token in the crossing chunk ----------------
    if (wave == 0) {
        float segsum = csum[lane * 2] + csum[lane * 2 + 1];
        float incl = wincl(segsum, lane);
        float total = __shfl(incl, 63, 64);            // Z_kept
        const float U = uvec[b] * total;
        unsigned long long mk = __ballot(incl >= U);
        int token;
        if (mk == 0ULL) {
            token = Vv;
        } else {
            int fl = __ffsll(mk) - 1;
            float base = __shfl(incl, fl, 64) - __shfl(segsum, fl, 64);
            float v = (lane < 2) ? csum[fl * 2 + lane] : 0.f;
            float incl2 = wincl(v, lane);
            unsigned long long mk2 = __ballot((lane < 2) && (base + incl2 >= U));
            int k2i = mk2 ? (__ffsll(mk2) - 1) : 1;
            int cx = fl * 2 + k2i;                     // crossing chunk
            float B = base + __shfl(incl2, k2i, 64) - __shfl(v, k2i, 64);
            int cb = cx << 10;
            float vv[16];
#pragma unroll
            for (int rr = 0; rr < 16; rr++) {
                int idx = cb + rr * 64 + lane;
                vv[rr] = (idx < Vv) ? row[idx] : -1e30f;
            }
            int cnt2 = 0;
#pragma unroll
            for (int rr = 0; rr < 16; rr++) {
                int idx = cb + rr * 64 + lane;
                unsigned kk = OKEY(__float_as_uint(vv[rr]));
                float e = __expf(vv[rr] * inv_t);
                float keep = (kk >= Tlow) ? e : 0.f;
                float is = wincl(keep, lane);
                unsigned long long mm = __ballot((idx < Vv) && (B + is < U));
                cnt2 += __popcll(mm);
                B += __shfl(is, 63, 64);
            }
            token = cb + cnt2;
        }
        if (lane == 0) out[b] = (token < Vv - 1) ? token : (Vv - 1);
    }
}

extern "C" void kernel_launch(void* const* d_in, const int* in_sizes, int n_in,
                              void* d_out, int out_size, void* d_ws, size_t ws_size,
                              hipStream_t stream) {
    const float* logits = (const float*)d_in[0];
    const float* u = (const float*)d_in[1];
    const int* temp = (const int*)d_in[2];
    int* out = (int*)d_out;
    int B = in_sizes[1];
    int V = in_sizes[0] / B;
    NucleusSampling_79336635892529_kernel<<<B, BLOCK, 0, stream>>>(logits, u, temp, out, V);
}